// Round 11
// baseline (508.993 us; speedup 1.0000x reference)
//
#include <hip/hip_runtime.h>
#include <cstdint>
#include <cstddef>

// ---------------------------------------------------------------------------
// GraphAttentionHead: out = elu(softmax(mask(LeakyReLU(mu_i + xi_j))) @ h)
// Round 22: barrier-free j-split attention, NO spill (R17 structure x R19
// register discipline).
//   R17's 216us was spill-death ((512,2)=128-VGPR cap vs ~230 live), not a
//   structural verdict; its barrier-free design was never cleanly tested.
//   The barrier-synced core models to ~15us pipe work + ~45us adj DRAM yet
//   measures ~135 across 11 variants -> discriminate {pattern-BW ceiling}
//   vs {barrier lockstep} with the clean j-split:
//   k_gatt17: block 32i x 256n x 8192j, 8 waves j-split (1024j each),
//   acc[2][16]=128, bfv quarters, 1-step adj reg-prefetch, live ~225<256
//   (launch_bounds(512,1), no scratch). B direct from L2-resident ht
//   (1GB agg = 10TB/s << 34.5 L2 ceiling). E/F exp staged once in 64KB LDS.
//   ZERO main-loop barriers. Epilogue: R17's proven LDS tree-reduce +
//   /Z + ELU + direct out store. nump (128MB traffic) + k_final DELETED.
//   Pipeline: prep_wt + gemm1m + gatt17 (3 kernels).
// ---------------------------------------------------------------------------

#define LOG2E 1.44269504f

typedef __attribute__((ext_vector_type(8))) short short8;   // 8 bf16 = 4 VGPRs
typedef __attribute__((ext_vector_type(4))) float floatx4;  // MFMA acc

using uint_as1 = __attribute__((address_space(1))) unsigned int;
using uint_as3 = __attribute__((address_space(3))) unsigned int;

__device__ __forceinline__ void gld_lds16(const void* g, void* l) {
  __builtin_amdgcn_global_load_lds((const uint_as1*)g, (uint_as3*)l, 16, 0, 0);
}

__device__ __forceinline__ unsigned short f2b(float f) {  // fp32 -> bf16 RNE (finite)
  unsigned u = __float_as_uint(f);
  u += 0x7fffu + ((u >> 16) & 1u);
  return (unsigned short)(u >> 16);
}

// packed RNE convert: lo16 = bf16(a), hi16 = bf16(b) — single VALU op
__device__ __forceinline__ unsigned cvtpk_bf16(float a, float b) {
  unsigned r;
  asm("v_cvt_pk_bf16_f32 %0, %1, %2" : "=v"(r) : "v"(a), "v"(b));
  return r;
}

// ------------------- K0b: W_phi [512][256] -> Wt bf16 [256][512] ------------
__global__ void k_prep_wt(const float* __restrict__ w, unsigned short* __restrict__ wt) {
  int tid = blockIdx.x * 256 + threadIdx.x;
  int n = tid >> 9, k = tid & 511;
  wt[n * 512 + k] = f2b(w[k * 256 + n]);
}

// ------ K1: h_t = (features @ W_phi)^T (bf16 MFMA) + mu/xi partials ---------
__global__ __launch_bounds__(256, 2) void k_gemm1m(const float* __restrict__ f,
                                                   const unsigned short* __restrict__ wt,
                                                   const float* __restrict__ wmu,
                                                   const float* __restrict__ wxi,
                                                   unsigned short* __restrict__ ht,
                                                   float* __restrict__ mupart,
                                                   float* __restrict__ xipart) {
  __shared__ __align__(16) unsigned short As[64 * 64];
  __shared__ __align__(16) unsigned short Bs[128 * 64];
  __shared__ float musum[4][64];
  __shared__ float xisum[4][64];
  int t = threadIdx.x, w = t >> 6, l = t & 63;
  int bm_ = blockIdx.x >> 1, bn = blockIdx.x & 1;
  int m0 = bm_ * 64, n0 = bn * 128;
  int lr = l >> 3, lg = l & 7, g = lg ^ lr;
  int kg = l >> 4, ln = l & 15;
  floatx4 zero = {0.f, 0.f, 0.f, 0.f};
  floatx4 acc[4][2];
#pragma unroll
  for (int mf = 0; mf < 4; ++mf)
#pragma unroll
    for (int nf = 0; nf < 2; ++nf) acc[mf][nf] = zero;

  for (int it = 0; it < 8; ++it) {
    int k0 = it * 64;
#pragma unroll
    for (int q = 0; q < 2; ++q) {
      int row = w * 16 + q * 8 + lr;
      const float* fp = f + (size_t)(m0 + row) * 512 + k0 + g * 8;
      float4 v0 = *(const float4*)fp;
      float4 v1 = *(const float4*)(fp + 4);
      uint4 d = {cvtpk_bf16(v0.x, v0.y), cvtpk_bf16(v0.z, v0.w),
                 cvtpk_bf16(v1.x, v1.y), cvtpk_bf16(v1.z, v1.w)};
      *(uint4*)&As[row * 64 + lg * 8] = d;
    }
#pragma unroll
    for (int q = 0; q < 4; ++q) {
      int row = w * 32 + q * 8 + lr;
      const void* gp = wt + (size_t)(n0 + row) * 512 + k0 + g * 8;
      int lb = __builtin_amdgcn_readfirstlane((w * 32 + q * 8) * 64);
      gld_lds16(gp, &Bs[lb]);
    }
    __syncthreads();
#pragma unroll
    for (int ks = 0; ks < 2; ++ks) {
      int gg = ks * 4 + kg;
      int swz = (gg ^ (ln & 7)) * 8;
      short8 bfr[2];
#pragma unroll
      for (int nf = 0; nf < 2; ++nf)
        bfr[nf] = *(const short8*)&Bs[(w * 32 + nf * 16 + ln) * 64 + swz];
#pragma unroll
      for (int mf = 0; mf < 4; ++mf) {
        short8 afr = *(const short8*)&As[(mf * 16 + ln) * 64 + swz];
#pragma unroll
        for (int nf = 0; nf < 2; ++nf)
          acc[mf][nf] = __builtin_amdgcn_mfma_f32_16x16x32_bf16(afr, bfr[nf], acc[mf][nf], 0, 0, 0);
      }
    }
    __syncthreads();
  }
#pragma unroll
  for (int mf = 0; mf < 4; ++mf)
#pragma unroll
    for (int nf = 0; nf < 2; ++nf) {
      int ng = n0 + w * 32 + nf * 16 + ln;
      int mg = m0 + mf * 16 + kg * 4;
      ushort4 o = {f2b(acc[mf][nf][0]), f2b(acc[mf][nf][1]),
                   f2b(acc[mf][nf][2]), f2b(acc[mf][nf][3])};
      *(ushort4*)&ht[(size_t)ng * 8192 + mg] = o;
    }
  float wma = wmu[n0 + w * 32 + ln], wmb = wmu[n0 + w * 32 + 16 + ln];
  float wxa = wxi[n0 + w * 32 + ln], wxb = wxi[n0 + w * 32 + 16 + ln];
#pragma unroll
  for (int mf = 0; mf < 4; ++mf)
#pragma unroll
    for (int r = 0; r < 4; ++r) {
      float ms = acc[mf][0][r] * wma + acc[mf][1][r] * wmb;
      float xs = acc[mf][0][r] * wxa + acc[mf][1][r] * wxb;
      ms += __shfl_xor(ms, 1); ms += __shfl_xor(ms, 2);
      ms += __shfl_xor(ms, 4); ms += __shfl_xor(ms, 8);
      xs += __shfl_xor(xs, 1); xs += __shfl_xor(xs, 2);
      xs += __shfl_xor(xs, 4); xs += __shfl_xor(xs, 8);
      if (ln == 0) {
        musum[w][mf * 16 + kg * 4 + r] = ms;
        xisum[w][mf * 16 + kg * 4 + r] = xs;
      }
    }
  __syncthreads();
  if (t < 64) {
    float m_ = musum[0][t] + musum[1][t] + musum[2][t] + musum[3][t];
    mupart[(size_t)bn * 8192 + m0 + t] = m_;
  } else if (t < 128) {
    int r = t - 64;
    float x_ = xisum[0][r] + xisum[1][r] + xisum[2][r] + xisum[3][r];
    xipart[(size_t)bn * 8192 + m0 + r] = x_;
  }
}

// ------------- K3: barrier-free j-split fused attention ---------------------
// grid 256 (=8192/32 i-rows), 512 thr = 8 waves; wave w owns j in
// [w*1024,(w+1)*1024), all waves compute the SAME 32i x 256n output tile.
// Per 32j step: adj -> per-lane regs (1-step prefetch), E/F from LDS,
// A-build + cvt_pk, B-frags (quarters of 4) direct from L2-resident ht,
// 32 MFMA. NO barriers in main loop. Epilogue: z shfl+zb reduce, acc
// tree-reduce via 128KB LDS (aliases E/F), wave0: /Z + ELU + store out.
__global__ __launch_bounds__(512, 1) void k_gatt17(const int* __restrict__ adjm,
                                                   const unsigned short* __restrict__ ht,
                                                   const float* __restrict__ mupart,
                                                   const float* __restrict__ xipart,
                                                   float* __restrict__ out) {
  __shared__ __align__(16) char smem[131072];  // main: E 32K + F 32K; epi: red 128K
  __shared__ __align__(16) float zb[8][32];
  __shared__ float zinv_s[32];

  float* EfE = (float*)smem;             // [8192]
  float* EfF = (float*)(smem + 32768);   // [8192]

  int t = threadIdx.x, w = t >> 6, l = t & 63;
  int ln = l & 15, kg = l >> 4;
  int i0 = blockIdx.x * 32;
  int jw0 = w * 1024;

  // ---- prologue: exp staging for ALL 8192 j from xi partial sums ----
#pragma unroll
  for (int q = 0; q < 4; ++q) {
    int idx = q * 2048 + t * 4;
    float4 xa = *(const float4*)&xipart[idx];
    float4 xb = *(const float4*)&xipart[8192 + idx];
    float x0 = (xa.x + xb.x) * LOG2E, x1 = (xa.y + xb.y) * LOG2E;
    float x2 = (xa.z + xb.z) * LOG2E, x3 = (xa.w + xb.w) * LOG2E;
    EfE[idx + 0] = __builtin_amdgcn_exp2f(x0);
    EfE[idx + 1] = __builtin_amdgcn_exp2f(x1);
    EfE[idx + 2] = __builtin_amdgcn_exp2f(x2);
    EfE[idx + 3] = __builtin_amdgcn_exp2f(x3);
    EfF[idx + 0] = __builtin_amdgcn_exp2f(0.2f * x0);
    EfF[idx + 1] = __builtin_amdgcn_exp2f(0.2f * x1);
    EfF[idx + 2] = __builtin_amdgcn_exp2f(0.2f * x2);
    EfF[idx + 3] = __builtin_amdgcn_exp2f(0.2f * x3);
  }
  float EM[2], FM[2];
#pragma unroll
  for (int mf = 0; mf < 2; ++mf) {
    int i = i0 + mf * 16 + ln;
    float mu = (mupart[i] + mupart[8192 + i]) * LOG2E;
    EM[mf] = __builtin_amdgcn_exp2f(mu);
    FM[mf] = __builtin_amdgcn_exp2f(0.2f * mu);
  }
  __syncthreads();  // E/F visible to all waves

  floatx4 zero = {0.f, 0.f, 0.f, 0.f};
  floatx4 acc[2][16];
#pragma unroll
  for (int mf = 0; mf < 2; ++mf)
#pragma unroll
    for (int nf = 0; nf < 16; ++nf) acc[mf][nf] = zero;
  float zacc[2] = {0.f, 0.f};

  // per-lane streams
  const int* ar0 = adjm + (size_t)(i0 + ln) * 8192 + jw0 + kg * 8;
  const int* ar1 = ar0 + (size_t)16 * 8192;
  const unsigned short* hb = ht + (size_t)ln * 8192 + jw0 + kg * 8;

  // adj prefetch set (1 step)
  int4 ac0 = *(const int4*)(ar0 + 0);
  int4 ac1 = *(const int4*)(ar0 + 4);
  int4 ac2 = *(const int4*)(ar1 + 0);
  int4 ac3 = *(const int4*)(ar1 + 4);

  for (int ks = 0; ks < 32; ++ks) {
    int joff = ks * 32;
    int jl = jw0 + joff + kg * 8;
    float4 e0 = *(const float4*)&EfE[jl];
    float4 e1 = *(const float4*)&EfE[jl + 4];
    float4 f0 = *(const float4*)&EfF[jl];
    float4 f1 = *(const float4*)&EfF[jl + 4];
    // prefetch next step's adj (issued before consuming current)
    int4 an0, an1, an2, an3;
    if (ks < 31) {
      an0 = *(const int4*)(ar0 + joff + 32);
      an1 = *(const int4*)(ar0 + joff + 36);
      an2 = *(const int4*)(ar1 + joff + 32);
      an3 = *(const int4*)(ar1 + joff + 36);
    }
    // A-build from register adj
    short8 af[2];
#pragma unroll
    for (int mf = 0; mf < 2; ++mf) {
      int av[8];
      if (mf == 0) {
        av[0] = ac0.x; av[1] = ac0.y; av[2] = ac0.z; av[3] = ac0.w;
        av[4] = ac1.x; av[5] = ac1.y; av[6] = ac1.z; av[7] = ac1.w;
      } else {
        av[0] = ac2.x; av[1] = ac2.y; av[2] = ac2.z; av[3] = ac2.w;
        av[4] = ac3.x; av[5] = ac3.y; av[6] = ac3.z; av[7] = ac3.w;
      }
      float ex[8] = {e0.x, e0.y, e0.z, e0.w, e1.x, e1.y, e1.z, e1.w};
      float fx[8] = {f0.x, f0.y, f0.z, f0.w, f1.x, f1.y, f1.z, f1.w};
      float A = EM[mf], F = FM[mf];
      union { unsigned u[4]; short8 s; } cv;
      float zs = 0.f;
#pragma unroll
      for (int p = 0; p < 4; ++p) {
        float m0 = fmaxf(A * ex[2 * p], F * fx[2 * p]);
        float m1 = fmaxf(A * ex[2 * p + 1], F * fx[2 * p + 1]);
        m0 = (av[2 * p] != 0) ? m0 : 0.f;
        m1 = (av[2 * p + 1] != 0) ? m1 : 0.f;
        zs += m0;
        zs += m1;
        cv.u[p] = cvtpk_bf16(m0, m1);  // lo=elem 2p, hi=elem 2p+1
      }
      zacc[mf] += zs;
      af[mf] = cv.s;
    }
    // B direct from global (ht L2-resident), quarters of 4
#pragma unroll
    for (int qtr = 0; qtr < 4; ++qtr) {
      short8 bfv[4];
#pragma unroll
      for (int nf = 0; nf < 4; ++nf)
        bfv[nf] = *(const short8*)&hb[(size_t)(qtr * 64 + nf * 16) * 8192 + joff];
#pragma unroll
      for (int mf = 0; mf < 2; ++mf)
#pragma unroll
        for (int nf = 0; nf < 4; ++nf)
          acc[mf][qtr * 4 + nf] = __builtin_amdgcn_mfma_f32_16x16x32_bf16(
              af[mf], bfv[nf], acc[mf][qtr * 4 + nf], 0, 0, 0);
    }
    ac0 = an0; ac1 = an1; ac2 = an2; ac3 = an3;
  }

  // ---- epilogue: Z ----
#pragma unroll
  for (int mf = 0; mf < 2; ++mf) {
    float z = zacc[mf];
    z += __shfl_xor(z, 16);
    z += __shfl_xor(z, 32);
    if (l < 16) zb[w][mf * 16 + l] = z;
  }
  __syncthreads();  // zb ready; all waves done with E/F -> red may reuse smem
  if (t < 32) {
    float z = 0.f;
#pragma unroll
    for (int p = 0; p < 8; ++p) z += zb[p][t];
    zinv_s[t] = 1.0f / z;
  }

  // ---- epilogue: acc tree reduction (4 slots x 32KB; e=(mf*16+nf)) ----
  float* red = (float*)smem;
#define RED_W(slot_)                                                        \
  {                                                                         \
    float* dst = red + (slot_) * 8192;                                      \
    _Pragma("unroll")                                                       \
    for (int mf = 0; mf < 2; ++mf)                                          \
      _Pragma("unroll")                                                     \
      for (int nf = 0; nf < 16; ++nf)                                       \
        *(floatx4*)&dst[(mf * 16 + nf) * 256 + l * 4] = acc[mf][nf];        \
  }
#define RED_R(slot_)                                                        \
  {                                                                         \
    const float* src = red + (slot_) * 8192;                                \
    _Pragma("unroll")                                                       \
    for (int mf = 0; mf < 2; ++mf)                                          \
      _Pragma("unroll")                                                     \
      for (int nf = 0; nf < 16; ++nf)                                       \
        acc[mf][nf] += *(const floatx4*)&src[(mf * 16 + nf) * 256 + l * 4]; \
  }
  if (w >= 4) RED_W(w - 4);
  __syncthreads();
  if (w < 4) RED_R(w);
  __syncthreads();
  if (w == 2 || w == 3) RED_W(w - 2);
  __syncthreads();
  if (w < 2) RED_R(w);
  __syncthreads();
  if (w == 1) RED_W(0);
  __syncthreads();
  if (w == 0) {
    RED_R(0);
#pragma unroll
    for (int mf = 0; mf < 2; ++mf)
#pragma unroll
      for (int nf = 0; nf < 16; ++nf)
#pragma unroll
        for (int r = 0; r < 4; ++r) {
          int row = mf * 16 + kg * 4 + r;
          float val = acc[mf][nf][r] * zinv_s[row];
          val = (val > 0.f) ? val : (__builtin_amdgcn_exp2f(val * LOG2E) - 1.f);
          out[(size_t)(i0 + row) * 256 + nf * 16 + ln] = val;
        }
  }
#undef RED_W
#undef RED_R
}

// ---------------------------------------------------------------------------
extern "C" void kernel_launch(void* const* d_in, const int* in_sizes, int n_in,
                              void* d_out, int out_size, void* d_ws, size_t ws_size,
                              hipStream_t stream) {
  const float* features = (const float*)d_in[0];
  const int* adjm = (const int*)d_in[1];
  const float* W_phi = (const float*)d_in[2];
  const float* w_mu = (const float*)d_in[3];
  const float* w_xi = (const float*)d_in[4];
  float* out = (float*)d_out;

  char* ws = (char*)d_ws;
  unsigned short* ht  = (unsigned short*)(ws + 0);         // 256x8192 bf16 = 4 MB
  unsigned short* wt  = (unsigned short*)(ws + 4194304);   // 256x512 bf16 = 256 KB
  float* mupart = (float*)(ws + 4456448);                  // 2x8192 f32 = 64 KB
  float* xipart = (float*)(ws + 4521984);                  // 2x8192 f32 = 64 KB

  k_prep_wt<<<512, 256, 0, stream>>>(W_phi, wt);
  k_gemm1m<<<256, 256, 0, stream>>>(features, wt, w_mu, w_xi, ht, mupart, xipart);
  k_gatt17<<<256, 512, 0, stream>>>(adjm, ht, mupart, xipart, out);
}

// Round 12
// 445.039 us; speedup vs baseline: 1.1437x; 1.1437x over previous
//
#include <hip/hip_runtime.h>
#include <cstdint>
#include <cstddef>

// ---------------------------------------------------------------------------
// GraphAttentionHead: out = elu(softmax(mask(LeakyReLU(mu_i + xi_j))) @ h)
// Round 23: TWO-PHASE gatt — adj streamed at FULL GRANULE, bit-compressed.
//   Session invariant identified: every fused variant touched adj rows in
//   128B granules (65k interleaved streams) -> ~2.2TB/s DRAM effective ->
//   gatt ~135-140us regardless of sync/occupancy/path (R14..R21 all null;
//   R17/R22 profiles: all pipes idle). bitmaskz streamed rows sequentially
//   at >=256B -> 6TB/s.
//   k_gatt18: Phase 1 = each wave streams its 32 adj rows sequentially
//   (1KB/instr), 16 ballots/row compress to bits[4][4][256] LDS (32KB);
//   B-stage(0,1) issued BEFORE phase 1 (hidden under it). Phase 2 = R21
//   window loop, adj loads replaced by broadcast ds_read_b64 bit reads
//   (bit-identical mask math, same Z order). vmcnt ledger unchanged.
// ---------------------------------------------------------------------------

#define LOG2E 1.44269504f

typedef __attribute__((ext_vector_type(8))) short short8;   // 8 bf16 = 4 VGPRs
typedef __attribute__((ext_vector_type(4))) float floatx4;  // MFMA acc

using uint_as1 = __attribute__((address_space(1))) unsigned int;
using uint_as3 = __attribute__((address_space(3))) unsigned int;

__device__ __forceinline__ void gld_lds16(const void* g, void* l) {
  __builtin_amdgcn_global_load_lds((const uint_as1*)g, (uint_as3*)l, 16, 0, 0);
}

__device__ __forceinline__ unsigned short f2b(float f) {  // fp32 -> bf16 RNE (finite)
  unsigned u = __float_as_uint(f);
  u += 0x7fffu + ((u >> 16) & 1u);
  return (unsigned short)(u >> 16);
}

// packed RNE convert: lo16 = bf16(a), hi16 = bf16(b) — single VALU op
__device__ __forceinline__ unsigned cvtpk_bf16(float a, float b) {
  unsigned r;
  asm("v_cvt_pk_bf16_f32 %0, %1, %2" : "=v"(r) : "v"(a), "v"(b));
  return r;
}

// ------------------- K0b: W_phi [512][256] -> Wt bf16 [256][512] ------------
__global__ void k_prep_wt(const float* __restrict__ w, unsigned short* __restrict__ wt) {
  int tid = blockIdx.x * 256 + threadIdx.x;
  int n = tid >> 9, k = tid & 511;
  wt[n * 512 + k] = f2b(w[k * 256 + n]);
}

// ------ K1: h_t = (features @ W_phi)^T (bf16 MFMA) + mu/xi partials ---------
__global__ __launch_bounds__(256, 2) void k_gemm1m(const float* __restrict__ f,
                                                   const unsigned short* __restrict__ wt,
                                                   const float* __restrict__ wmu,
                                                   const float* __restrict__ wxi,
                                                   unsigned short* __restrict__ ht,
                                                   float* __restrict__ mupart,
                                                   float* __restrict__ xipart) {
  __shared__ __align__(16) unsigned short As[64 * 64];
  __shared__ __align__(16) unsigned short Bs[128 * 64];
  __shared__ float musum[4][64];
  __shared__ float xisum[4][64];
  int t = threadIdx.x, w = t >> 6, l = t & 63;
  int bm_ = blockIdx.x >> 1, bn = blockIdx.x & 1;
  int m0 = bm_ * 64, n0 = bn * 128;
  int lr = l >> 3, lg = l & 7, g = lg ^ lr;
  int kg = l >> 4, ln = l & 15;
  floatx4 zero = {0.f, 0.f, 0.f, 0.f};
  floatx4 acc[4][2];
#pragma unroll
  for (int mf = 0; mf < 4; ++mf)
#pragma unroll
    for (int nf = 0; nf < 2; ++nf) acc[mf][nf] = zero;

  for (int it = 0; it < 8; ++it) {
    int k0 = it * 64;
#pragma unroll
    for (int q = 0; q < 2; ++q) {
      int row = w * 16 + q * 8 + lr;
      const float* fp = f + (size_t)(m0 + row) * 512 + k0 + g * 8;
      float4 v0 = *(const float4*)fp;
      float4 v1 = *(const float4*)(fp + 4);
      uint4 d = {cvtpk_bf16(v0.x, v0.y), cvtpk_bf16(v0.z, v0.w),
                 cvtpk_bf16(v1.x, v1.y), cvtpk_bf16(v1.z, v1.w)};
      *(uint4*)&As[row * 64 + lg * 8] = d;
    }
#pragma unroll
    for (int q = 0; q < 4; ++q) {
      int row = w * 32 + q * 8 + lr;
      const void* gp = wt + (size_t)(n0 + row) * 512 + k0 + g * 8;
      int lb = __builtin_amdgcn_readfirstlane((w * 32 + q * 8) * 64);
      gld_lds16(gp, &Bs[lb]);
    }
    __syncthreads();
#pragma unroll
    for (int ks = 0; ks < 2; ++ks) {
      int gg = ks * 4 + kg;
      int swz = (gg ^ (ln & 7)) * 8;
      short8 bfr[2];
#pragma unroll
      for (int nf = 0; nf < 2; ++nf)
        bfr[nf] = *(const short8*)&Bs[(w * 32 + nf * 16 + ln) * 64 + swz];
#pragma unroll
      for (int mf = 0; mf < 4; ++mf) {
        short8 afr = *(const short8*)&As[(mf * 16 + ln) * 64 + swz];
#pragma unroll
        for (int nf = 0; nf < 2; ++nf)
          acc[mf][nf] = __builtin_amdgcn_mfma_f32_16x16x32_bf16(afr, bfr[nf], acc[mf][nf], 0, 0, 0);
      }
    }
    __syncthreads();
  }
#pragma unroll
  for (int mf = 0; mf < 4; ++mf)
#pragma unroll
    for (int nf = 0; nf < 2; ++nf) {
      int ng = n0 + w * 32 + nf * 16 + ln;
      int mg = m0 + mf * 16 + kg * 4;
      ushort4 o = {f2b(acc[mf][nf][0]), f2b(acc[mf][nf][1]),
                   f2b(acc[mf][nf][2]), f2b(acc[mf][nf][3])};
      *(ushort4*)&ht[(size_t)ng * 8192 + mg] = o;
    }
  float wma = wmu[n0 + w * 32 + ln], wmb = wmu[n0 + w * 32 + 16 + ln];
  float wxa = wxi[n0 + w * 32 + ln], wxb = wxi[n0 + w * 32 + 16 + ln];
#pragma unroll
  for (int mf = 0; mf < 4; ++mf)
#pragma unroll
    for (int r = 0; r < 4; ++r) {
      float ms = acc[mf][0][r] * wma + acc[mf][1][r] * wmb;
      float xs = acc[mf][0][r] * wxa + acc[mf][1][r] * wxb;
      ms += __shfl_xor(ms, 1); ms += __shfl_xor(ms, 2);
      ms += __shfl_xor(ms, 4); ms += __shfl_xor(ms, 8);
      xs += __shfl_xor(xs, 1); xs += __shfl_xor(xs, 2);
      xs += __shfl_xor(xs, 4); xs += __shfl_xor(xs, 8);
      if (ln == 0) {
        musum[w][mf * 16 + kg * 4 + r] = ms;
        xisum[w][mf * 16 + kg * 4 + r] = xs;
      }
    }
  __syncthreads();
  if (t < 64) {
    float m_ = musum[0][t] + musum[1][t] + musum[2][t] + musum[3][t];
    mupart[(size_t)bn * 8192 + m0 + t] = m_;
  } else if (t < 128) {
    int r = t - 64;
    float x_ = xisum[0][r] + xisum[1][r] + xisum[2][r] + xisum[3][r];
    xipart[(size_t)bn * 8192 + m0 + r] = x_;
  }
}

// ------------- K3: two-phase fused attention GEMM ---------------------------
// grid 256 = 8 jb x 32 ig. Block 256i x 256n x 1024j; 8 waves i-split,
// wave 32i x 256n (mf=2, nf=16 in QUARTERS of 4), acc[2][16].
// Phase 1: wave w streams adj rows w*32..w*32+31 of its 1024-j slice
// sequentially (1KB/instr), __ballot-compresses to bits[4][4][256] (32KB
// LDS; bit l of bits[chunk][c][row] = adj[row][chunk*256+4l+c] != 0).
// Phase 2: 32 windows x 32j; Bs quad-buffer gld_lds + vmcnt(2) skeleton
// (R19/R21); A-build mask from broadcast ds_read_b64 bit reads.
__global__ __launch_bounds__(512, 1) void k_gatt18(const int* __restrict__ adjm,
                                                   const unsigned short* __restrict__ ht,
                                                   const float* __restrict__ mupart,
                                                   const float* __restrict__ xipart,
                                                   float* __restrict__ nump,
                                                   float* __restrict__ zpart) {
  __shared__ __align__(16) unsigned short Bs[4][256 * 32];       // 64 KB
  __shared__ __align__(16) unsigned long long bitsA[4][4][256];  // 32 KB
  __shared__ __align__(16) float EfE[1024];                      // 4 KB
  __shared__ __align__(16) float EfF[1024];                      // 4 KB

  int t = threadIdx.x, w = t >> 6, l = t & 63;
  int ln = l & 15, kg = l >> 4;
  int jb = blockIdx.x & 7, ig = blockIdx.x >> 3;
  int i0 = ig * 256;
  int jc0 = jb * 1024;

  // ---- prologue: xi -> exp staging (halves: t<256 does E, t>=256 does F) ----
  {
    int t2 = t & 255;
    float4 xa = *(const float4*)&xipart[jc0 + t2 * 4];
    float4 xb = *(const float4*)&xipart[8192 + jc0 + t2 * 4];
    float x0 = (xa.x + xb.x) * LOG2E, x1 = (xa.y + xb.y) * LOG2E;
    float x2 = (xa.z + xb.z) * LOG2E, x3 = (xa.w + xb.w) * LOG2E;
    if (t < 256) {
      EfE[t2 * 4 + 0] = __builtin_amdgcn_exp2f(x0);
      EfE[t2 * 4 + 1] = __builtin_amdgcn_exp2f(x1);
      EfE[t2 * 4 + 2] = __builtin_amdgcn_exp2f(x2);
      EfE[t2 * 4 + 3] = __builtin_amdgcn_exp2f(x3);
    } else {
      EfF[t2 * 4 + 0] = __builtin_amdgcn_exp2f(0.2f * x0);
      EfF[t2 * 4 + 1] = __builtin_amdgcn_exp2f(0.2f * x1);
      EfF[t2 * 4 + 2] = __builtin_amdgcn_exp2f(0.2f * x2);
      EfF[t2 * 4 + 3] = __builtin_amdgcn_exp2f(0.2f * x3);
    }
  }

  float EM[2], FM[2];
#pragma unroll
  for (int mf = 0; mf < 2; ++mf) {
    int i = i0 + w * 32 + mf * 16 + ln;
    float mu = (mupart[i] + mupart[8192 + i]) * LOG2E;
    EM[mf] = __builtin_amdgcn_exp2f(mu);
    FM[mf] = __builtin_amdgcn_exp2f(0.2f * mu);
  }

  floatx4 zero = {0.f, 0.f, 0.f, 0.f};
  floatx4 acc[2][16];
#pragma unroll
  for (int mf = 0; mf < 2; ++mf)
#pragma unroll
    for (int nf = 0; nf < 16; ++nf) acc[mf][nf] = zero;
  float zacc[2] = {0.f, 0.f};

  // Bs window: 256 n-rows x 32j; 2 gld_lds/wave. Source granule pre-swizzled
  // so reader slot kg^((n>>1)&3) yields granule kg.
#define STAGE_B(win_, b_)                                                   \
  {                                                                         \
    int j0_ = jc0 + (win_) * 32;                                            \
    _Pragma("unroll")                                                       \
    for (int q = 0; q < 2; ++q) {                                           \
      int rowbase = w * 32 + q * 16;                                        \
      int row = rowbase + (l >> 2);                                         \
      int g = (l & 3) ^ ((row >> 1) & 3);                                   \
      const void* gp = ht + (size_t)row * 8192 + j0_ + g * 8;               \
      int lb = __builtin_amdgcn_readfirstlane((b_) * (256 * 32) + rowbase * 32); \
      gld_lds16(gp, &((unsigned short*)Bs)[lb]);                            \
    }                                                                       \
  }

  // issue B stage(0,1) BEFORE phase 1 — lands during the adj stream
  STAGE_B(0, 0);
  STAGE_B(1, 1);

  // ---- PHASE 1: stream this wave's 32 adj rows sequentially, compress ----
  {
    const int* rp_base = adjm + (size_t)(i0 + w * 32) * 8192 + jc0;
    for (int r8 = 0; r8 < 32; ++r8) {
      const int* rp = rp_base + (size_t)r8 * 8192;
      // 4 chunks x 1KB contiguous (lane l: ints chunk*256 + 4l .. +3)
      int4 v0 = *(const int4*)(rp + 4 * l);
      int4 v1 = *(const int4*)(rp + 256 + 4 * l);
      int4 v2 = *(const int4*)(rp + 512 + 4 * l);
      int4 v3 = *(const int4*)(rp + 768 + 4 * l);
      int row = w * 32 + r8;
#define BALLOT4(vv, ch)                                                     \
      {                                                                     \
        unsigned long long b0 = __ballot(vv.x != 0);                        \
        unsigned long long b1 = __ballot(vv.y != 0);                        \
        unsigned long long b2 = __ballot(vv.z != 0);                        \
        unsigned long long b3 = __ballot(vv.w != 0);                        \
        if (l < 4) {                                                        \
          unsigned long long bs = (l == 0) ? b0 : (l == 1) ? b1             \
                                  : (l == 2) ? b2 : b3;                     \
          bitsA[ch][l][row] = bs;                                           \
        }                                                                   \
      }
      BALLOT4(v0, 0)
      BALLOT4(v1, 1)
      BALLOT4(v2, 2)
      BALLOT4(v3, 3)
#undef BALLOT4
    }
  }
  __syncthreads();  // E/F + bits + stage(0,1) all landed (one-time drain)

  // ---- PHASE 2: window loop (R21 skeleton, adj from LDS bits) ----
  for (int win = 0; win < 32; ++win) {
    int bR = win & 3;
    // stage(win) landed; stage(win+1) stays in flight
    if (win < 31) {
      asm volatile("s_waitcnt vmcnt(2)" ::: "memory");
    } else {
      asm volatile("s_waitcnt vmcnt(0)" ::: "memory");
    }
    __builtin_amdgcn_s_barrier();   // all waves' stage(win) landed
    asm volatile("" ::: "memory");  // fence: no LDS reads hoist above barrier

    // E/F slice for this window (broadcast reads)
    int jl = win * 32 + kg * 8;
    float4 e0 = *(const float4*)&EfE[jl];
    float4 e1 = *(const float4*)&EfE[jl + 4];
    float4 f0 = *(const float4*)&EfF[jl];
    float4 f1 = *(const float4*)&EfF[jl + 4];

    // adj bits for this window: chunk/word index (uniform per win), shift p
    int j0 = win * 32 + kg * 8;
    int chunk = j0 >> 8;
    int p = (j0 & 255) >> 2;  // even, 0..62; bits p,p+1 of each word c

    // A-build from LDS bits
    short8 af[2];
#pragma unroll
    for (int mf = 0; mf < 2; ++mf) {
      int row_local = w * 32 + mf * 16 + ln;
      unsigned long long q0 = bitsA[chunk][0][row_local] >> p;
      unsigned long long q1 = bitsA[chunk][1][row_local] >> p;
      unsigned long long q2 = bitsA[chunk][2][row_local] >> p;
      unsigned long long q3 = bitsA[chunk][3][row_local] >> p;
      int av[8];
      av[0] = (int)(q0 & 1); av[1] = (int)(q1 & 1);
      av[2] = (int)(q2 & 1); av[3] = (int)(q3 & 1);
      av[4] = (int)((q0 >> 1) & 1); av[5] = (int)((q1 >> 1) & 1);
      av[6] = (int)((q2 >> 1) & 1); av[7] = (int)((q3 >> 1) & 1);
      float ex[8] = {e0.x, e0.y, e0.z, e0.w, e1.x, e1.y, e1.z, e1.w};
      float fx[8] = {f0.x, f0.y, f0.z, f0.w, f1.x, f1.y, f1.z, f1.w};
      float A = EM[mf], F = FM[mf];
      union { unsigned u[4]; short8 s; } cv;
      float zs = 0.f;
#pragma unroll
      for (int pp = 0; pp < 4; ++pp) {
        float m0 = fmaxf(A * ex[2 * pp], F * fx[2 * pp]);
        float m1 = fmaxf(A * ex[2 * pp + 1], F * fx[2 * pp + 1]);
        m0 = (av[2 * pp] != 0) ? m0 : 0.f;
        m1 = (av[2 * pp + 1] != 0) ? m1 : 0.f;
        zs += m0;
        zs += m1;
        cv.u[pp] = cvtpk_bf16(m0, m1);  // lo=elem 2pp, hi=elem 2pp+1
      }
      zacc[mf] += zs;
      af[mf] = cv.s;
    }
    // four quarters of 4 B-frags (live bfv = 16 VGPR)
#pragma unroll
    for (int qtr = 0; qtr < 4; ++qtr) {
      short8 bfv[4];
#pragma unroll
      for (int nf = 0; nf < 4; ++nf) {
        int n = qtr * 64 + nf * 16 + ln;
        bfv[nf] = *(const short8*)&Bs[bR][n * 32 + ((kg ^ ((n >> 1) & 3)) * 8)];
      }
#pragma unroll
      for (int mf = 0; mf < 2; ++mf)
#pragma unroll
        for (int nf = 0; nf < 4; ++nf)
          acc[mf][qtr * 4 + nf] = __builtin_amdgcn_mfma_f32_16x16x32_bf16(
              af[mf], bfv[nf], acc[mf][qtr * 4 + nf], 0, 0, 0);
    }
    // issue next-next window staging (write target 2 windows from readers)
    if (win < 30) {
      STAGE_B(win + 2, (win + 2) & 3);
    }
  }
#undef STAGE_B

  // ---- epilogue: z partial (reduce over kg lanes) ----
#pragma unroll
  for (int mf = 0; mf < 2; ++mf) {
    float z = zacc[mf];
    z += __shfl_xor(z, 16);
    z += __shfl_xor(z, 32);
    if (l < 16) zpart[(size_t)jb * 8192 + i0 + w * 32 + mf * 16 + ln] = z;
  }

  // ---- epilogue: numerator partial (plain stores) ----
  float* np = nump + (size_t)jb * (8192 * 256);
#pragma unroll
  for (int mf = 0; mf < 2; ++mf) {
    int rowb = i0 + w * 32 + mf * 16 + kg * 4;
#pragma unroll
    for (int r = 0; r < 4; ++r) {
      float* rp = np + (size_t)(rowb + r) * 256;
#pragma unroll
      for (int nf = 0; nf < 16; ++nf)
        rp[nf * 16 + ln] = acc[mf][nf][r];
    }
  }
}

// ---------------- K4: finalize: sum 8 j-partials, /Z, ELU -------------------
__global__ void k_final(const float* __restrict__ nump, const float* __restrict__ zpart,
                        float* __restrict__ out) {
  int tid = blockIdx.x * 256 + threadIdx.x;  // x4 floats
  int i = tid >> 6;
  float z = 0.f;
#pragma unroll
  for (int p = 0; p < 8; ++p) z += zpart[(size_t)p * 8192 + i];
  float zi = 1.0f / z;
  float4 v = {0.f, 0.f, 0.f, 0.f};
#pragma unroll
  for (int p = 0; p < 8; ++p) {
    float4 s = *(const float4*)&nump[(size_t)p * (8192 * 256) + tid * 4];
    v.x += s.x; v.y += s.y; v.z += s.z; v.w += s.w;
  }
  v.x *= zi; v.y *= zi; v.z *= zi; v.w *= zi;
  v.x = (v.x > 0.f) ? v.x : (__builtin_amdgcn_exp2f(v.x * LOG2E) - 1.f);
  v.y = (v.y > 0.f) ? v.y : (__builtin_amdgcn_exp2f(v.y * LOG2E) - 1.f);
  v.z = (v.z > 0.f) ? v.z : (__builtin_amdgcn_exp2f(v.z * LOG2E) - 1.f);
  v.w = (v.w > 0.f) ? v.w : (__builtin_amdgcn_exp2f(v.w * LOG2E) - 1.f);
  *(float4*)&out[tid * 4] = v;
}

// ---------------------------------------------------------------------------
extern "C" void kernel_launch(void* const* d_in, const int* in_sizes, int n_in,
                              void* d_out, int out_size, void* d_ws, size_t ws_size,
                              hipStream_t stream) {
  const float* features = (const float*)d_in[0];
  const int* adjm = (const int*)d_in[1];
  const float* W_phi = (const float*)d_in[2];
  const float* w_mu = (const float*)d_in[3];
  const float* w_xi = (const float*)d_in[4];
  float* out = (float*)d_out;

  char* ws = (char*)d_ws;
  unsigned short* ht  = (unsigned short*)(ws + 0);         // 256x8192 bf16 = 4 MB
  unsigned short* wt  = (unsigned short*)(ws + 4194304);   // 256x512 bf16 = 256 KB
  float* mupart = (float*)(ws + 4456448);                  // 2x8192 f32 = 64 KB
  float* xipart = (float*)(ws + 4521984);                  // 2x8192 f32 = 64 KB
  float* zpart  = (float*)(ws + 4587520);                  // 8x8192 f32 = 256 KB
  float* nump   = (float*)(ws + 8388608);                  // 8 x 8 MB partials

  k_prep_wt<<<512, 256, 0, stream>>>(W_phi, wt);
  k_gemm1m<<<256, 256, 0, stream>>>(features, wt, w_mu, w_xi, ht, mupart, xipart);
  k_gatt18<<<256, 512, 0, stream>>>(adjm, ht, mupart, xipart, nump, zpart);
  k_final<<<2048, 256, 0, stream>>>(nump, zpart, out);
}